// Round 3
// baseline (297.894 us; speedup 1.0000x reference)
//
#include <hip/hip_runtime.h>

// SoftmaxCascade: B=8192 rows, E=4681 nodes, 8-ary implicit heap
// (children of p = 8p+1..8p+8). out[0]=1; out[i]=exp(x[i]+D[(i-1)>>3]) where
// D[g]=adj[g]+x[g]+D[parent(g)], D[0]=adj[0], adj[g]=-m-log(sum exp(x_c-m)).
//
// R5 post-mortem: three different load strategies all ~92us with ALL pipes
// idle (VALU 34%, HBM 32%) => the serial per-block phase chain
// {issue -> vmcnt(0) drain -> compute -> store -> end} exposes full memory
// latency on every block's critical path.
// R6: persistent double-buffered pipeline (T3/T4 at row granularity):
//  - grid = 768 (3 blocks/CU, LDS-bound), each block loops ~11 rows
//  - DMA row i+1 into buf B issued BEFORE computing row i from buf A
//  - counted s_waitcnt vmcnt(4): drains row i's 21 loads (every wave has
//    >=4 younger stores from row i-1), leaves next-row DMA in flight
//  - raw s_barrier + manual lgkmcnt (NOT __syncthreads: its lowering emits
//    vmcnt(0) before the barrier and would kill the pipeline)
//  - staging keeps R5's pad-9 layout (2-way bank aliasing = free); pads/OOB
//    lanes load harmless dups so per-wave load count is statically 21
//  - incremental (off, r) DMA addressing: no per-iteration division

constexpr int E     = 4681;
constexpr int NG    = 585;              // sibling groups (internal nodes)
constexpr int NSLOT = 5266;             // valid slots; slot(i) = 9*(i>>3)+(i&7)
constexpr int BUF   = 5376;             // 21*256 slots DMA-covered per buffer
constexpr int GRID  = 768;              // 3 blocks/CU * 256 CU; 768 % 4 == 0

__device__ __forceinline__ int xslot(int i) { return 9 * (i >> 3) + (i & 7); }

__device__ __forceinline__ void async_ld(const float* g, float* l) {
    __builtin_amdgcn_global_load_lds(
        (const __attribute__((address_space(1))) void*)g,
        (__attribute__((address_space(3))) void*)l, 4, 0, 0);
}

// DMA one row into xb (pad-9 permuted via per-lane global addresses, linear
// LDS dest). Exactly 21 load instructions per wave, branchless:
//   slot s = 256j + tid, global off = 8*(s/9) + s%9, maintained incrementally
//   (s += 256 => q += 28, r += 4 with wrap: off += 228 / 227).
// Pad slots (r==8) load the previous element (overwritten by adj later);
// slots >= NSLOT (j==20, tid>=146) load rin[0] into junk slots (never read).
__device__ __forceinline__ void stage(const float* __restrict__ rin, float* xb,
                                      int tid, int q0, int r0) {
    const int lbase = tid & ~63;                 // wave-uniform LDS base
    int off = 8 * q0 + r0;
    int r = r0;
    #pragma unroll
    for (int j = 0; j < 21; ++j) {
        int a = (r == 8) ? (off - 1) : off;      // pad slot: harmless dup
        if (j == 20) a = (tid < NSLOT - 5120) ? a : 0;   // tid < 146 valid
        async_ld(rin + a, xb + 256 * j + lbase);
        const bool wrap = (r >= 5);              // r + 4 >= 9
        off += wrap ? 227 : 228;
        r   += wrap ? -5 : 4;
    }
}

__device__ __forceinline__ float group_adj(const float w[8]) {
    float m = w[0];
    #pragma unroll
    for (int k = 1; k < 8; ++k) m = fmaxf(m, w[k]);
    float s = 0.0f;
    #pragma unroll
    for (int k = 0; k < 8; ++k) s += __expf(w[k] - m);
    return -m - __logf(s);
}

__device__ __forceinline__ void rdwin(const float* xs, int g, float w[8]) {
    const float* b = xs + 9 * g;                 // nodes 8g+1..8g+8 at b[1..7], b[9]
    #pragma unroll
    for (int k = 0; k < 7; ++k) w[k] = b[1 + k];
    w[7] = b[9];
}

// D(g) = adj(g) + sum over ancestors a of (x(a) + adj(parent(a))), depth<=3.
__device__ __forceinline__ float walkD(const float* xs, int g, float adjv) {
    float D = adjv;
    if (g > 0) {
        const int p = (g - 1) >> 3;
        D += xs[xslot(g)] + xs[9 * p + 8];            // x(g) + adj(p)
        if (p > 0) {
            const int pp = (p - 1) >> 3;
            D += xs[xslot(p)] + xs[9 * pp + 8];       // x(p) + adj(pp)
            if (pp > 0) D += xs[xslot(pp)] + xs[8];   // x(pp) + adj(root grp)
        }
    }
    return D;
}

// Store exp(x[8g+1+t]+D) -> rout[8g+1+t], t=0..7. Global float index of
// rout+8g+1 === S (mod 4): natural-alignment segments, block-uniform S.
template<int S>
__device__ __forceinline__ void emit(float* __restrict__ rout, const float* xs,
                                     int g, float D) {
    float y[8];
    {
        const float* b = xs + 9 * g;
        #pragma unroll
        for (int k = 0; k < 7; ++k) y[k] = __expf(b[1 + k] + D);
        y[7] = __expf(b[9] + D);
    }
    float* q = rout + 8 * g + 1;
    if (S == 0) {
        *(float4*)(q)     = make_float4(y[0], y[1], y[2], y[3]);
        *(float4*)(q + 4) = make_float4(y[4], y[5], y[6], y[7]);
    } else if (S == 1) {
        q[0] = y[0];
        *(float2*)(q + 1) = make_float2(y[1], y[2]);
        *(float4*)(q + 3) = make_float4(y[3], y[4], y[5], y[6]);
        q[7] = y[7];
    } else if (S == 2) {
        *(float2*)(q)     = make_float2(y[0], y[1]);
        *(float4*)(q + 2) = make_float4(y[2], y[3], y[4], y[5]);
        *(float2*)(q + 6) = make_float2(y[6], y[7]);
    } else {
        q[0] = y[0];
        *(float4*)(q + 1) = make_float4(y[1], y[2], y[3], y[4]);
        *(float2*)(q + 5) = make_float2(y[5], y[6]);
        q[7] = y[7];
    }
}

// Phase B (adj -> pad slots) | lgkm drain + barrier | phase C (walk + stores).
// Min global-store count per wave is 4 (S==0, waves 2/3) -> vmcnt(4) is the
// safe counted wait at the NEXT iteration's top.
template<int S>
__device__ __forceinline__ void compute_row(float* xb, float* __restrict__ rout,
                                            int tid) {
    const int g0 = tid, g1 = tid + 256, g2 = tid + 512;
    const bool h2 = (g2 < NG);                   // tid < 73
    float w[8];
    rdwin(xb, g0, w); const float a0 = group_adj(w);
    rdwin(xb, g1, w); const float a1 = group_adj(w);
    float a2 = 0.f;
    if (h2) { rdwin(xb, g2, w); a2 = group_adj(w); }
    xb[9 * g0 + 8] = a0;                         // pads: disjoint from windows
    xb[9 * g1 + 8] = a1;
    if (h2) xb[9 * g2 + 8] = a2;
    asm volatile("s_waitcnt lgkmcnt(0)" ::: "memory");   // pad writes visible
    __builtin_amdgcn_sched_barrier(0);
    __builtin_amdgcn_s_barrier();
    __builtin_amdgcn_sched_barrier(0);
    emit<S>(rout, xb, g0, walkD(xb, g0, a0));
    emit<S>(rout, xb, g1, walkD(xb, g1, a1));
    if (h2) emit<S>(rout, xb, g2, walkD(xb, g2, a2));
    if (tid == 0) rout[0] = 1.0f;                // root probability
}

template<int S>
__device__ __forceinline__ void run(const float* __restrict__ in,
                                    float* __restrict__ out,
                                    float* b0, float* b1, int tid, int bid, int B) {
    const int q0 = tid / 9, r0 = tid % 9;        // one division, reused per row
    float* xb = b0;                              // buffer being computed
    float* xo = b1;                              // buffer being DMA'd
    stage(in + (long long)bid * E, xb, tid, q0, r0);   // prologue: row0 in flight
    for (int row = bid; row < B; row += GRID) {
        // drain this row's loads; leave next-row DMA (not yet issued) free.
        // First iter: nothing younger outstanding -> full drain.
        if (row == bid) { asm volatile("s_waitcnt vmcnt(0)" ::: "memory"); }
        else            { asm volatile("s_waitcnt vmcnt(4)" ::: "memory"); }
        __builtin_amdgcn_sched_barrier(0);
        __builtin_amdgcn_s_barrier();            // also fences prev row's reads
        __builtin_amdgcn_sched_barrier(0);
        const int nxt = row + GRID;
        if (nxt < B) stage(in + (long long)nxt * E, xo, tid, q0, r0);
        __builtin_amdgcn_sched_barrier(0);       // pin: DMA issued before compute
        compute_row<S>(xb, out + (long long)row * E, tid);
        float* t = xb; xb = xo; xo = t;          // swap buffers
    }
}

__global__ __launch_bounds__(256, 3) void cascade_kernel(const float* __restrict__ in,
                                                         float* __restrict__ out,
                                                         int B) {
    __shared__ float b0[BUF], b1[BUF];           // 2 x 21 KB -> 3 blocks/CU
    const int tid = threadIdx.x;
    const int bid = blockIdx.x;
    // store alignment: global index of rout+8g+1 === (row+1) mod 4; GRID%4==0
    // and E%4==1 -> S = (bid+1)&3 is uniform across all of this block's rows.
    switch ((bid + 1) & 3) {
        case 0: run<0>(in, out, b0, b1, tid, bid, B); break;
        case 1: run<1>(in, out, b0, b1, tid, bid, B); break;
        case 2: run<2>(in, out, b0, b1, tid, bid, B); break;
        case 3: run<3>(in, out, b0, b1, tid, bid, B); break;
    }
}

extern "C" void kernel_launch(void* const* d_in, const int* in_sizes, int n_in,
                              void* d_out, int out_size, void* d_ws, size_t ws_size,
                              hipStream_t stream) {
    const float* in = (const float*)d_in[0];     // [B, E] float32
    float* out = (float*)d_out;                  // [B, E] float32
    const int B = in_sizes[0] / E;               // 8192
    const int grid = (B < GRID) ? B : GRID;
    cascade_kernel<<<grid, 256, 0, stream>>>(in, out, B);
}